// Round 12
// baseline (412.123 us; speedup 1.0000x reference)
//
#include <hip/hip_runtime.h>
#include <hip/hip_bf16.h>

#define N_NODES 30000
#define N_EDGES 480000
#define D_IN    1000
#define KPAD    1024
#define NHEAD   8
#define F_HID   32
#define D_EMB   64
#define NEG_SLOPE 0.2f
#define MAXDEG  64

typedef __attribute__((ext_vector_type(4))) float  f32x4;
typedef __attribute__((ext_vector_type(8))) __bf16 bf16x8;
typedef __attribute__((ext_vector_type(4))) __bf16 bf16x4;

// ---------------------------------------------------------------------------
// cvt_w: LDS-tiled WbT transpose (coalesced W reads) | small transposes |
// WaT fold | XCD-sharded edge scatter.
// ---------------------------------------------------------------------------
#define WBT_TILES   64                        // 16 k-tiles x 4 n-tiles
#define REST_TOT    (D_EMB*256 + F_HID*D_EMB + D_IN*F_HID)   // 50432
#define REST_BLOCKS ((REST_TOT + 255) / 256)  // 198
#define WA_BLOCKS   (16 * KPAD / 256)         // 64
#define SC_CHUNK    4068                      // ceil(480000/118)
#define SC_BLOCKS   (118 * 8)                 // 944

__global__ __launch_bounds__(256) void cvt_w(
    const float* __restrict__ W, const float* __restrict__ emb_W,
    const float* __restrict__ d1, const float* __restrict__ d2,
    const float* __restrict__ att_src, const float* __restrict__ att_dst,
    __bf16* __restrict__ WbT, __bf16* __restrict__ embT,
    __bf16* __restrict__ d1T, __bf16* __restrict__ d2T,
    __bf16* __restrict__ WaT,
    const int* __restrict__ eidx, int* __restrict__ cnt,
    int* __restrict__ slots)
{
    int b = blockIdx.x;
    if (b < WBT_TILES) {
        // 64x64 LDS-tiled transpose: W[1000][256] fp32 -> WbT[256][1024] bf16
        __shared__ float tile[64][65];        // +1 pad: conflict-free transpose
        const int kt = b >> 2, nt = b & 3;
        const int k0 = kt * 64, n0 = nt * 64;
        const int r = threadIdx.x >> 6;       // 0..3
        const int c = threadIdx.x & 63;
        #pragma unroll
        for (int j = 0; j < 16; j++) {
            int row = j * 4 + r;
            int k = k0 + row;
            tile[row][c] = (k < D_IN) ? W[(size_t)k * 256 + n0 + c] : 0.0f;
        }
        __syncthreads();
        #pragma unroll
        for (int j = 0; j < 16; j++) {
            int nrow = j * 4 + r;
            WbT[(size_t)(n0 + nrow) * KPAD + k0 + c] = (__bf16)tile[c][nrow];
        }
        return;
    }
    b -= WBT_TILES;
    if (b < REST_BLOCKS) {
        int i = b * 256 + threadIdx.x;
        if (i < D_EMB * 256) {                // embT [64][256]
            int n = i >> 8, k = i & 255;
            embT[i] = (__bf16)emb_W[(size_t)k * D_EMB + n];
            return;
        }
        i -= D_EMB * 256;
        if (i < F_HID * D_EMB) {              // d1T [32][64]
            int n = i >> 6, k = i & 63;
            d1T[i] = (__bf16)d1[(size_t)k * F_HID + n];
            return;
        }
        i -= F_HID * D_EMB;
        if (i < D_IN * F_HID) {               // d2T [1000][32]
            int n = i >> 5, k = i & 31;
            d2T[i] = (__bf16)d2[(size_t)k * D_IN + n];
        }
        return;
    }
    b -= REST_BLOCKS;
    if (b < WA_BLOCKS) {                      // WaT [16][1024]
        int i = b * 256 + threadIdx.x;
        int j = i >> 10, k = i & 1023;
        float s = 0.f;
        if (k < D_IN) {
            const float* av = (j < 8 ? att_src : att_dst) + (j & 7) * F_HID;
            const float* wr = W + (size_t)k * 256 + (j & 7) * F_HID;
            #pragma unroll
            for (int f = 0; f < F_HID; f++) s += wr[f] * av[f];
        }
        WaT[i] = (__bf16)s;
        return;
    }
    b -= WA_BLOCKS;
    {
        // ---- XCD-sharded edge scatter (cnt pre-zeroed via memsetAsync) ----
        const int shard = blockIdx.x & 7;
        const int chunk = b >> 3;                 // 0..117
        int e0 = chunk * SC_CHUNK;
        int e1 = e0 + SC_CHUNK; if (e1 > N_EDGES) e1 = N_EDGES;
        for (int e = e0 + (int)threadIdx.x; e < e1; e += 256) {
            int d = eidx[N_EDGES + e];
            if (((d >> 4) & 7) == shard) {
                int slot = atomicAdd(&cnt[d], 1);
                slots[d * MAXDEG + slot] = eidx[e];
            }
        }
    }
}

// ---------------------------------------------------------------------------
// bf16 MFMA GEMM staging (m97 structure), XOR chunk swizzle.
// ---------------------------------------------------------------------------
__device__ __forceinline__ void stage_tile(
    __bf16* lds, const __bf16* __restrict__ g, int base, int maxr,
    int K, int k0, int rows, int w, int lane, int stride)
{
    const int rsub = lane >> 2;
    const int c    = lane & 3;
    for (int off = w * 1024; off < rows * 64; off += stride) {
        int r  = (off >> 6) + rsub;
        int gr = base + r; gr = gr > maxr ? maxr : gr;
        int chunk = c ^ (r & 3);
        const __bf16* gp = g + (size_t)gr * K + k0 + chunk * 8;
        __builtin_amdgcn_global_load_lds(
            (const __attribute__((address_space(1))) void*)gp,
            (__attribute__((address_space(3))) void*)((char*)lds + off),
            16, 0, 0);
    }
}

// ---------------------------------------------------------------------------
// gemm1: h = x @ W, BM=64 x BN=256, 512 threads, LDS double-buffered,
// T14 issue-early/write-late phases. launch_bounds(512,6) -> 3 blocks/CU.
// ---------------------------------------------------------------------------
#define GEMM1_BLOCKS ((N_NODES + 63) / 64)       // 469

__device__ __forceinline__ void xload8(const float* __restrict__ xrow, int cb,
                                       f32x4& u0, f32x4& u1)
{
    if (cb < D_IN) {
        const f32x4* p = (const f32x4*)(xrow + cb);
        u0 = p[0]; u1 = p[1];
    } else {
        u0 = (f32x4){0.f, 0.f, 0.f, 0.f};
        u1 = (f32x4){0.f, 0.f, 0.f, 0.f};
    }
}

__device__ __forceinline__ bf16x8 cvt8(const f32x4& u0, const f32x4& u1)
{
    bf16x8 o;
    o[0] = (__bf16)u0.x; o[1] = (__bf16)u0.y; o[2] = (__bf16)u0.z; o[3] = (__bf16)u0.w;
    o[4] = (__bf16)u1.x; o[5] = (__bf16)u1.y; o[6] = (__bf16)u1.z; o[7] = (__bf16)u1.w;
    return o;
}

__global__ __launch_bounds__(512, 6) void gemm1_fused(
    const float* __restrict__ x, const __bf16* __restrict__ WbT,
    const __bf16* __restrict__ WaT, __bf16* __restrict__ hb,
    float* __restrict__ a_s, float* __restrict__ a_d, int M)
{
    __shared__ __align__(16) __bf16 As[2][64 * 32];    // 2 x 4KB
    __shared__ __align__(16) __bf16 Bs[2][256 * 32];   // 2 x 16KB

    const int tid  = threadIdx.x;
    const int w    = tid >> 6, lane = tid & 63;
    const int wm   = w >> 2,   wn   = w & 3;           // 2x4 waves, 32x64 each
    const int quad = lane >> 4, l16 = lane & 15;
    const int bm   = blockIdx.x * 64;

    const bool astage = (tid < 256);
    const int r0   = tid >> 2;
    const int cpos = tid & 3;
    const int cxor = (cpos ^ (r0 & 3)) << 3;
    int grow = bm + r0; if (grow > M - 1) grow = M - 1;
    const float* xrow = x + (size_t)grow * D_IN;

    const int brsub = lane >> 2;
    const int bc    = lane & 3;

    f32x4 acc[2][4];
    #pragma unroll
    for (int i = 0; i < 2; i++)
        #pragma unroll
        for (int j = 0; j < 4; j++)
            acc[i][j] = (f32x4){0.f, 0.f, 0.f, 0.f};
    f32x4 accA[2];
    #pragma unroll
    for (int i = 0; i < 2; i++) accA[i] = (f32x4){0.f, 0.f, 0.f, 0.f};

    const bool att = (wn == 0);
    const __bf16* warow = WaT + (size_t)l16 * KPAD + quad * 8;

    auto stageB = [&](int buf, int k0) {
        #pragma unroll
        for (int off = 0; off < 16384; off += 8192) {
            int o2 = off + w * 1024;
            int r = (o2 >> 6) + brsub;
            int chunk = bc ^ (r & 3);
            const __bf16* gp = WbT + (size_t)r * KPAD + k0 + chunk * 8;
            __builtin_amdgcn_global_load_lds(
                (const __attribute__((address_space(1))) void*)gp,
                (__attribute__((address_space(3))) void*)((char*)&Bs[buf][0] + o2),
                16, 0, 0);
        }
    };

    auto compute = [&](int buf, const bf16x8& attfrag) {
        bf16x8 af[2], bfr[4];
        #pragma unroll
        for (int mt = 0; mt < 2; mt++) {
            int r = wm * 32 + mt * 16 + l16;
            af[mt] = *(const bf16x8*)&As[buf][r * 32 + (quad ^ (r & 3)) * 8];
        }
        #pragma unroll
        for (int nt = 0; nt < 4; nt++) {
            int r = wn * 64 + nt * 16 + l16;
            bfr[nt] = *(const bf16x8*)&Bs[buf][r * 32 + (quad ^ (r & 3)) * 8];
        }
        #pragma unroll
        for (int mt = 0; mt < 2; mt++)
            #pragma unroll
            for (int nt = 0; nt < 4; nt++)
                acc[mt][nt] = __builtin_amdgcn_mfma_f32_16x16x32_bf16(
                    af[mt], bfr[nt], acc[mt][nt], 0, 0, 0);
        if (att) {
            #pragma unroll
            for (int mt = 0; mt < 2; mt++)
                accA[mt] = __builtin_amdgcn_mfma_f32_16x16x32_bf16(
                    af[mt], attfrag, accA[mt], 0, 0, 0);
        }
    };

    // prologue: prep buf0 for k=0
    f32x4 x0, x1;
    if (astage) xload8(xrow, 0 + cxor, x0, x1);
    bf16x8 attc = {};
    if (att) attc = *(const bf16x8*)(warow + 0);
    stageB(0, 0);
    if (astage) *(bf16x8*)&As[0][r0 * 32 + cpos * 8] = cvt8(x0, x1);
    __syncthreads();

    #pragma unroll 2
    for (int p = 0; p < 32; ++p) {
        const int buf = p & 1;
        const int kn  = (p + 1) * 32;
        bf16x8 attn = {};
        if (p < 31) {
            if (astage) xload8(xrow, kn + cxor, x0, x1);
            if (att) attn = *(const bf16x8*)(warow + kn);
            stageB(buf ^ 1, kn);
        }
        compute(buf, attc);
        __builtin_amdgcn_sched_barrier(0);     // pin cvt/ds_write BELOW MFMAs
        if (p < 31) {
            if (astage) *(bf16x8*)&As[buf ^ 1][r0 * 32 + cpos * 8] = cvt8(x0, x1);
        }
        attc = attn;
        __syncthreads();
    }

    // epilogue: hb bf16
    #pragma unroll
    for (int nt = 0; nt < 4; nt++) {
        int col = wn * 64 + nt * 16 + l16;
        #pragma unroll
        for (int mt = 0; mt < 2; mt++) {
            int row0 = bm + wm * 32 + mt * 16 + quad * 4;
            #pragma unroll
            for (int rr = 0; rr < 4; rr++) {
                int row = row0 + rr;
                if (row < M)
                    hb[(size_t)row * 256 + col] = (__bf16)acc[mt][nt][rr];
            }
        }
    }
    if (att) {
        #pragma unroll
        for (int mt = 0; mt < 2; mt++) {
            int row0 = bm + wm * 32 + mt * 16 + quad * 4;
            #pragma unroll
            for (int rr = 0; rr < 4; rr++) {
                int row = row0 + rr;
                if (row < M) {
                    float v = accA[mt][rr];
                    if (l16 < 8) a_s[row * NHEAD + l16] = v;
                    else         a_d[row * NHEAD + (l16 - 8)] = v;
                }
            }
        }
    }
}

// ---------------------------------------------------------------------------
// FUSED gat_aggregate + gemm_zdr. Block = 64 nodes, 512 threads (8 waves).
// r12: phase 1 DE-BARRIERED (embT fragments direct from L2-hot global; the
// 16 per-step barrier drains deleted), Bs buffer removed (LDS 54->49KB),
// launch_bounds(512,6) -> 3 blocks/CU for gather-latency hiding.
// ---------------------------------------------------------------------------
#define HROW 264

__device__ __forceinline__ float leaky(float x) {
    return x > 0.f ? x : NEG_SLOPE * x;
}

__global__ __launch_bounds__(512, 6) void gat_zdr(
    const __bf16* __restrict__ hb, const float* __restrict__ a_s,
    const float* __restrict__ a_d, const int* __restrict__ cnt,
    const int* __restrict__ slots, const float* __restrict__ bias,
    const __bf16* __restrict__ embT, const __bf16* __restrict__ d1T,
    const __bf16* __restrict__ d2T, const float* __restrict__ emb_b,
    const float* __restrict__ dec_b1, const float* __restrict__ dec_b2,
    float* __restrict__ z, float* __restrict__ recon, int M)
{
    __shared__ __align__(16) __bf16 hgatS[64 * HROW];   // 33 KB
    __shared__ __align__(16) __bf16 zS[64 * 64];        // 8 KB
    __shared__ __align__(16) __bf16 Bs2[2 * 32 * 32];   // 4 KB (d1T)
    __shared__ __align__(16) __bf16 dS[64 * 32];        // 4 KB

    const int tid  = threadIdx.x;
    const int wv   = tid >> 6, lane = tid & 63;
    const int quad = lane >> 4, l16 = lane & 15;
    const int bm   = blockIdx.x * 64;

    // stage d1T once (waves 0,1 active inside stage_tile's loop)
    stage_tile(Bs2,        d1T, 0, 31, 64, 0,  32, wv, lane, 4096);
    stage_tile(Bs2 + 1024, d1T, 0, 31, 64, 32, 32, wv, lane, 4096);

    // ---- phase 0: GAT aggregation, dual-node interleaved chains ----
    {
        const int hh = lane >> 3;
        const int fo = (lane & 7) * 4;
        const f32x4 bv = *(const f32x4*)(bias + lane * 4);

        auto gather4 = [&](int base, int e, float adn, f32x4& acc, float& denom) {
            const int4 ss = *(const int4*)(slots + base + e);
            float l0 = a_s[ss.x * NHEAD + hh], l1 = a_s[ss.y * NHEAD + hh];
            float l2 = a_s[ss.z * NHEAD + hh], l3 = a_s[ss.w * NHEAD + hh];
            bf16x4 h0 = *(const bf16x4*)(hb + (size_t)ss.x * 256 + hh * F_HID + fo);
            bf16x4 h1 = *(const bf16x4*)(hb + (size_t)ss.y * 256 + hh * F_HID + fo);
            bf16x4 h2 = *(const bf16x4*)(hb + (size_t)ss.z * 256 + hh * F_HID + fo);
            bf16x4 h3 = *(const bf16x4*)(hb + (size_t)ss.w * 256 + hh * F_HID + fo);
            float p0 = __expf(leaky(l0 + adn)), p1 = __expf(leaky(l1 + adn));
            float p2 = __expf(leaky(l2 + adn)), p3 = __expf(leaky(l3 + adn));
            denom += (p0 + p1) + (p2 + p3);
            acc.x += p0*(float)h0[0] + p1*(float)h1[0] + p2*(float)h2[0] + p3*(float)h3[0];
            acc.y += p0*(float)h0[1] + p1*(float)h1[1] + p2*(float)h2[1] + p3*(float)h3[1];
            acc.z += p0*(float)h0[2] + p1*(float)h1[2] + p2*(float)h2[2] + p3*(float)h3[2];
            acc.w += p0*(float)h0[3] + p1*(float)h1[3] + p2*(float)h2[3] + p3*(float)h3[3];
        };
        auto gather1 = [&](int base, int e, float adn, f32x4& acc, float& denom) {
            int s = slots[base + e];
            float pe = __expf(leaky(a_s[s * NHEAD + hh] + adn));
            denom += pe;
            bf16x4 hv = *(const bf16x4*)(hb + (size_t)s * 256 + hh * F_HID + fo);
            acc.x += pe * (float)hv[0]; acc.y += pe * (float)hv[1];
            acc.z += pe * (float)hv[2]; acc.w += pe * (float)hv[3];
        };

        #pragma unroll
        for (int i = 0; i < 4; i++) {
            const int nA = bm + wv * 8 + i * 2;
            const int nB = nA + 1;
            const bool vA = nA < M, vB = nB < M;
            const int iA = vA ? nA : M - 1;
            const int iB = vB ? nB : M - 1;
            const int baseA = iA * MAXDEG, baseB = iB * MAXDEG;
            const int cA = vA ? cnt[iA] : 0;
            const int cB = vB ? cnt[iB] : 0;
            const float adnA = a_d[iA * NHEAD + hh];
            const float adnB = a_d[iB * NHEAD + hh];

            // self loops
            float pA = __expf(leaky(a_s[iA * NHEAD + hh] + adnA));
            float pB = __expf(leaky(a_s[iB * NHEAD + hh] + adnB));
            float denA = pA, denB = pB;
            f32x4 accA, accB;
            {
                bf16x4 hvA = *(const bf16x4*)(hb + (size_t)iA * 256 + hh * F_HID + fo);
                bf16x4 hvB = *(const bf16x4*)(hb + (size_t)iB * 256 + hh * F_HID + fo);
                accA.x = pA*(float)hvA[0]; accA.y = pA*(float)hvA[1];
                accA.z = pA*(float)hvA[2]; accA.w = pA*(float)hvA[3];
                accB.x = pB*(float)hvB[0]; accB.y = pB*(float)hvB[1];
                accB.z = pB*(float)hvB[2]; accB.w = pB*(float)hvB[3];
            }
            int eA = 0, eB = 0;
            while (eA + 8 <= cA && eB + 8 <= cB) {
                gather4(baseA, eA,     adnA, accA, denA);
                gather4(baseB, eB,     adnB, accB, denB);
                gather4(baseA, eA + 4, adnA, accA, denA);
                gather4(baseB, eB + 4, adnB, accB, denB);
                eA += 8; eB += 8;
            }
            while (eA + 8 <= cA) {
                gather4(baseA, eA, adnA, accA, denA);
                gather4(baseA, eA + 4, adnA, accA, denA);
                eA += 8;
            }
            while (eB + 8 <= cB) {
                gather4(baseB, eB, adnB, accB, denB);
                gather4(baseB, eB + 4, adnB, accB, denB);
                eB += 8;
            }
            if (eA + 4 <= cA) { gather4(baseA, eA, adnA, accA, denA); eA += 4; }
            if (eB + 4 <= cB) { gather4(baseB, eB, adnB, accB, denB); eB += 4; }
            for (; eA < cA; eA++) gather1(baseA, eA, adnA, accA, denA);
            for (; eB < cB; eB++) gather1(baseB, eB, adnB, accB, denB);

            if (vA) {
                float inv = 1.0f / denA;
                float o0 = accA.x * inv + bv.x, o1 = accA.y * inv + bv.y;
                float o2 = accA.z * inv + bv.z, o3 = accA.w * inv + bv.w;
                o0 = o0 > 0.f ? o0 : 0.f; o1 = o1 > 0.f ? o1 : 0.f;
                o2 = o2 > 0.f ? o2 : 0.f; o3 = o3 > 0.f ? o3 : 0.f;
                bf16x4 ob;
                ob[0] = (__bf16)o0; ob[1] = (__bf16)o1;
                ob[2] = (__bf16)o2; ob[3] = (__bf16)o3;
                *(bf16x4*)&hgatS[(wv * 8 + i * 2) * HROW + lane * 4] = ob;
            }
            if (vB) {
                float inv = 1.0f / denB;
                float o0 = accB.x * inv + bv.x, o1 = accB.y * inv + bv.y;
                float o2 = accB.z * inv + bv.z, o3 = accB.w * inv + bv.w;
                o0 = o0 > 0.f ? o0 : 0.f; o1 = o1 > 0.f ? o1 : 0.f;
                o2 = o2 > 0.f ? o2 : 0.f; o3 = o3 > 0.f ? o3 : 0.f;
                bf16x4 ob;
                ob[0] = (__bf16)o0; ob[1] = (__bf16)o1;
                ob[2] = (__bf16)o2; ob[3] = (__bf16)o3;
                *(bf16x4*)&hgatS[(wv * 8 + i * 2 + 1) * HROW + lane * 4] = ob;
            }
        }
    }
    __syncthreads();   // hgatS complete; also drains Bs2 gload_lds

    // ---- phase 1: z = hgatS @ embT, DE-BARRIERED ----
    // embT fragments read directly from global (32KB, L2-broadcast-hot):
    // 8 fragments/wave total. Zero barriers in the K-loop.
    const int wm  = wv >> 2;
    const int wn4 = wv & 3;
    f32x4 acc[2];
    acc[0] = (f32x4){0,0,0,0}; acc[1] = (f32x4){0,0,0,0};

    const __bf16* embrow = embT + (size_t)(wn4 * 16 + l16) * 256 + quad * 8;
    #pragma unroll
    for (int k0 = 0; k0 < 256; k0 += 32) {
        bf16x8 af[2];
        #pragma unroll
        for (int mt = 0; mt < 2; mt++) {
            int r = wm * 32 + mt * 16 + l16;
            af[mt] = *(const bf16x8*)&hgatS[r * HROW + k0 + quad * 8];
        }
        bf16x8 bfr = *(const bf16x8*)(embrow + k0);
        #pragma unroll
        for (int mt = 0; mt < 2; mt++)
            acc[mt] = __builtin_amdgcn_mfma_f32_16x16x32_bf16(af[mt], bfr, acc[mt], 0, 0, 0);
    }

    // epilogue 1: z fp32 -> global; z bf16 -> zS (stage_tile XOR layout)
    {
        int col = wn4 * 16 + l16;
        float bv = emb_b[col];
        int t = col >> 5, cch = (col >> 3) & 3, j = col & 7;
        #pragma unroll
        for (int mt = 0; mt < 2; mt++) {
            int rl0 = wm * 32 + mt * 16 + quad * 4;
            #pragma unroll
            for (int rr = 0; rr < 4; rr++) {
                int rl = rl0 + rr;
                int row = bm + rl;
                float v = acc[mt][rr] + bv;
                if (row < M) z[(size_t)row * D_EMB + col] = v;
                zS[t * 2048 + rl * 32 + (cch ^ (rl & 3)) * 8 + j] = (__bf16)v;
            }
        }
    }
    __syncthreads();

    // ---- phase 2: d = relu(zS @ d1T + b1), waves with wn4<2 ----
    if (wn4 < 2) {
        f32x4 accd[2];
        accd[0] = (f32x4){0,0,0,0}; accd[1] = (f32x4){0,0,0,0};
        #pragma unroll
        for (int t = 0; t < 2; t++) {
            bf16x8 af[2], bfr;
            #pragma unroll
            for (int mt = 0; mt < 2; mt++) {
                int r = wm * 32 + mt * 16 + l16;
                af[mt] = *(const bf16x8*)&zS[t * 2048 + r * 32 + (quad ^ (r & 3)) * 8];
            }
            {
                int r = wn4 * 16 + l16;
                bfr = *(const bf16x8*)&Bs2[t * 1024 + r * 32 + (quad ^ (r & 3)) * 8];
            }
            #pragma unroll
            for (int mt = 0; mt < 2; mt++)
                accd[mt] = __builtin_amdgcn_mfma_f32_16x16x32_bf16(af[mt], bfr, accd[mt], 0, 0, 0);
        }
        int col = wn4 * 16 + l16;
        float bv = dec_b1[col];
        int cc = col >> 3, j = col & 7;
        #pragma unroll
        for (int mt = 0; mt < 2; mt++) {
            int rl0 = wm * 32 + mt * 16 + quad * 4;
            #pragma unroll
            for (int rr = 0; rr < 4; rr++) {
                int rl = rl0 + rr;
                float v = accd[mt][rr] + bv;
                v = v > 0.f ? v : 0.f;
                dS[rl * 32 + (cc ^ (rl & 3)) * 8 + j] = (__bf16)v;
            }
        }
    }
    __syncthreads();

    // ---- phase 3: recon = d @ d2T + b2 (operand-swapped, f32x4 stores) ----
    {
        const int wtt = wv & 3;
        bf16x8 daf[2];
        #pragma unroll
        for (int mt = 0; mt < 2; mt++) {
            int r = wm * 32 + mt * 16 + l16;
            daf[mt] = *(const bf16x8*)&dS[r * 32 + (quad ^ (r & 3)) * 8];
        }
        for (int tt = wtt; tt < 63; tt += 4) {
            int crow = tt * 16 + l16;
            if (crow > D_IN - 1) crow = D_IN - 1;
            bf16x8 bfr = *(const bf16x8*)&d2T[(size_t)crow * 32 + quad * 8];
            f32x4 a[2];
            #pragma unroll
            for (int mt = 0; mt < 2; mt++) {
                a[mt] = (f32x4){0.f, 0.f, 0.f, 0.f};
                a[mt] = __builtin_amdgcn_mfma_f32_16x16x32_bf16(bfr, daf[mt], a[mt], 0, 0, 0);
            }
            int col0 = tt * 16 + quad * 4;
            if (col0 + 3 < D_IN) {
                f32x4 bv = *(const f32x4*)&dec_b2[col0];
                #pragma unroll
                for (int mt = 0; mt < 2; mt++) {
                    int row = bm + wm * 32 + mt * 16 + l16;
                    if (row < M) {
                        f32x4 o;
                        o.x = a[mt].x + bv.x; o.y = a[mt].y + bv.y;
                        o.z = a[mt].z + bv.z; o.w = a[mt].w + bv.w;
                        *(f32x4*)&recon[(size_t)row * D_IN + col0] = o;
                    }
                }
            }
        }
    }
}

// ---------------------------------------------------------------------------
extern "C" void kernel_launch(void* const* d_in, const int* in_sizes, int n_in,
                              void* d_out, int out_size, void* d_ws, size_t ws_size,
                              hipStream_t stream)
{
    const float* x        = (const float*)d_in[0];
    const int*   eidx     = (const int*)  d_in[1];
    const float* W        = (const float*)d_in[3];
    const float* att_src  = (const float*)d_in[4];
    const float* att_dst  = (const float*)d_in[5];
    const float* bias_gat = (const float*)d_in[6];
    const float* emb_W    = (const float*)d_in[7];
    const float* emb_b    = (const float*)d_in[8];
    const float* dec_W1   = (const float*)d_in[9];
    const float* dec_b1   = (const float*)d_in[10];
    const float* dec_W2   = (const float*)d_in[11];
    const float* dec_b2   = (const float*)d_in[12];

    float* out   = (float*)d_out;
    float* recon = out;                             // [30000,1000] fp32
    float* z     = out + (size_t)N_NODES * D_IN;    // [30000,64]   fp32

    char* ws = (char*)d_ws;
    size_t o = 0;
    auto alloc = [&](size_t bytes) { char* p = ws + o; o = (o + bytes + 255) & ~(size_t)255; return p; };
    __bf16* hb      = (__bf16*)alloc((size_t)N_NODES * 256 * 2);
    __bf16* WbT     = (__bf16*)alloc((size_t)256 * KPAD * 2);
    __bf16* embT    = (__bf16*)alloc((size_t)D_EMB * 256 * 2);
    __bf16* d1T     = (__bf16*)alloc((size_t)F_HID * D_EMB * 2);
    __bf16* d2T     = (__bf16*)alloc((size_t)D_IN * F_HID * 2);
    __bf16* WaT     = (__bf16*)alloc((size_t)16 * KPAD * 2);
    float*  a_s     = (float*) alloc((size_t)N_NODES * NHEAD * 4);
    float*  a_d     = (float*) alloc((size_t)N_NODES * NHEAD * 4);
    int*    slots   = (int*)   alloc((size_t)N_NODES * MAXDEG * 4);
    int*    cnt     = (int*)   alloc((size_t)N_NODES * 4);

    // 0. zero cnt (graph-capturable async memset)
    hipMemsetAsync(cnt, 0, (size_t)N_NODES * 4, stream);

    // 1. tiled weight transposes + WaT fold + XCD-sharded edge scatter
    cvt_w<<<WBT_TILES + REST_BLOCKS + WA_BLOCKS + SC_BLOCKS, 256, 0, stream>>>(
        W, emb_W, dec_W1, dec_W2, att_src, att_dst,
        WbT, embT, d1T, d2T, WaT, eidx, cnt, slots);

    // 2. h = x @ W -> hb bf16; a_s/a_d folded
    gemm1_fused<<<GEMM1_BLOCKS, 512, 0, stream>>>(
        x, WbT, WaT, hb, a_s, a_d, N_NODES);

    // 3. fused GAT aggregation + z + d + recon (de-barriered phase 1)
    gat_zdr<<<GEMM1_BLOCKS, 512, 0, stream>>>(
        hb, a_s, a_d, cnt, slots, bias_gat,
        embT, d1T, d2T, emb_b, dec_b1, dec_b2, z, recon, N_NODES);
}

// Round 13
// 350.267 us; speedup vs baseline: 1.1766x; 1.1766x over previous
//
#include <hip/hip_runtime.h>
#include <hip/hip_bf16.h>

#define N_NODES 30000
#define N_EDGES 480000
#define D_IN    1000
#define KPAD    1024
#define NHEAD   8
#define F_HID   32
#define D_EMB   64
#define NEG_SLOPE 0.2f
#define MAXDEG  64

typedef __attribute__((ext_vector_type(4))) float  f32x4;
typedef __attribute__((ext_vector_type(8))) __bf16 bf16x8;
typedef __attribute__((ext_vector_type(4))) __bf16 bf16x4;

// ---------------------------------------------------------------------------
// cvt_w: LDS-tiled WbT transpose (coalesced W reads) | small transposes |
// WaT fold | XCD-sharded edge scatter.
// ---------------------------------------------------------------------------
#define WBT_TILES   64                        // 16 k-tiles x 4 n-tiles
#define REST_TOT    (D_EMB*256 + F_HID*D_EMB + D_IN*F_HID)   // 50432
#define REST_BLOCKS ((REST_TOT + 255) / 256)  // 198
#define WA_BLOCKS   (16 * KPAD / 256)         // 64
#define SC_CHUNK    4068                      // ceil(480000/118)
#define SC_BLOCKS   (118 * 8)                 // 944

__global__ __launch_bounds__(256) void cvt_w(
    const float* __restrict__ W, const float* __restrict__ emb_W,
    const float* __restrict__ d1, const float* __restrict__ d2,
    const float* __restrict__ att_src, const float* __restrict__ att_dst,
    __bf16* __restrict__ WbT, __bf16* __restrict__ embT,
    __bf16* __restrict__ d1T, __bf16* __restrict__ d2T,
    __bf16* __restrict__ WaT,
    const int* __restrict__ eidx, int* __restrict__ cnt,
    int* __restrict__ slots)
{
    int b = blockIdx.x;
    if (b < WBT_TILES) {
        // 64x64 LDS-tiled transpose: W[1000][256] fp32 -> WbT[256][1024] bf16
        __shared__ float tile[64][65];        // +1 pad: conflict-free transpose
        const int kt = b >> 2, nt = b & 3;
        const int k0 = kt * 64, n0 = nt * 64;
        const int r = threadIdx.x >> 6;       // 0..3
        const int c = threadIdx.x & 63;
        #pragma unroll
        for (int j = 0; j < 16; j++) {
            int row = j * 4 + r;
            int k = k0 + row;
            tile[row][c] = (k < D_IN) ? W[(size_t)k * 256 + n0 + c] : 0.0f;
        }
        __syncthreads();
        #pragma unroll
        for (int j = 0; j < 16; j++) {
            int nrow = j * 4 + r;
            WbT[(size_t)(n0 + nrow) * KPAD + k0 + c] = (__bf16)tile[c][nrow];
        }
        return;
    }
    b -= WBT_TILES;
    if (b < REST_BLOCKS) {
        int i = b * 256 + threadIdx.x;
        if (i < D_EMB * 256) {                // embT [64][256]
            int n = i >> 8, k = i & 255;
            embT[i] = (__bf16)emb_W[(size_t)k * D_EMB + n];
            return;
        }
        i -= D_EMB * 256;
        if (i < F_HID * D_EMB) {              // d1T [32][64]
            int n = i >> 6, k = i & 63;
            d1T[i] = (__bf16)d1[(size_t)k * F_HID + n];
            return;
        }
        i -= F_HID * D_EMB;
        if (i < D_IN * F_HID) {               // d2T [1000][32]
            int n = i >> 5, k = i & 31;
            d2T[i] = (__bf16)d2[(size_t)k * D_IN + n];
        }
        return;
    }
    b -= REST_BLOCKS;
    if (b < WA_BLOCKS) {                      // WaT [16][1024]
        int i = b * 256 + threadIdx.x;
        int j = i >> 10, k = i & 1023;
        float s = 0.f;
        if (k < D_IN) {
            const float* av = (j < 8 ? att_src : att_dst) + (j & 7) * F_HID;
            const float* wr = W + (size_t)k * 256 + (j & 7) * F_HID;
            #pragma unroll
            for (int f = 0; f < F_HID; f++) s += wr[f] * av[f];
        }
        WaT[i] = (__bf16)s;
        return;
    }
    b -= WA_BLOCKS;
    {
        // ---- XCD-sharded edge scatter (cnt pre-zeroed via memsetAsync) ----
        const int shard = blockIdx.x & 7;
        const int chunk = b >> 3;                 // 0..117
        int e0 = chunk * SC_CHUNK;
        int e1 = e0 + SC_CHUNK; if (e1 > N_EDGES) e1 = N_EDGES;
        for (int e = e0 + (int)threadIdx.x; e < e1; e += 256) {
            int d = eidx[N_EDGES + e];
            if (((d >> 4) & 7) == shard) {
                int slot = atomicAdd(&cnt[d], 1);
                slots[d * MAXDEG + slot] = eidx[e];
            }
        }
    }
}

// ---------------------------------------------------------------------------
// bf16 MFMA GEMM staging (m97 structure), XOR chunk swizzle.
// ---------------------------------------------------------------------------
__device__ __forceinline__ void stage_tile(
    __bf16* lds, const __bf16* __restrict__ g, int base, int maxr,
    int K, int k0, int rows, int w, int lane, int stride)
{
    const int rsub = lane >> 2;
    const int c    = lane & 3;
    for (int off = w * 1024; off < rows * 64; off += stride) {
        int r  = (off >> 6) + rsub;
        int gr = base + r; gr = gr > maxr ? maxr : gr;
        int chunk = c ^ (r & 3);
        const __bf16* gp = g + (size_t)gr * K + k0 + chunk * 8;
        __builtin_amdgcn_global_load_lds(
            (const __attribute__((address_space(1))) void*)gp,
            (__attribute__((address_space(3))) void*)((char*)lds + off),
            16, 0, 0);
    }
}

// ---------------------------------------------------------------------------
// gemm1: h = x @ W, BM=64 x BN=256, 512 threads, LDS double-buffered,
// T14 issue-early/write-late phases. launch_bounds(512,4) — r11's measured
// config (VGPR 64). lb(512,6) REGRESSED: allocator squeezed to 40 VGPR
// (exactly the accumulator footprint) and spilled everything else.
// ---------------------------------------------------------------------------
#define GEMM1_BLOCKS ((N_NODES + 63) / 64)       // 469

__device__ __forceinline__ void xload8(const float* __restrict__ xrow, int cb,
                                       f32x4& u0, f32x4& u1)
{
    if (cb < D_IN) {
        const f32x4* p = (const f32x4*)(xrow + cb);
        u0 = p[0]; u1 = p[1];
    } else {
        u0 = (f32x4){0.f, 0.f, 0.f, 0.f};
        u1 = (f32x4){0.f, 0.f, 0.f, 0.f};
    }
}

__device__ __forceinline__ bf16x8 cvt8(const f32x4& u0, const f32x4& u1)
{
    bf16x8 o;
    o[0] = (__bf16)u0.x; o[1] = (__bf16)u0.y; o[2] = (__bf16)u0.z; o[3] = (__bf16)u0.w;
    o[4] = (__bf16)u1.x; o[5] = (__bf16)u1.y; o[6] = (__bf16)u1.z; o[7] = (__bf16)u1.w;
    return o;
}

__global__ __launch_bounds__(512, 4) void gemm1_fused(
    const float* __restrict__ x, const __bf16* __restrict__ WbT,
    const __bf16* __restrict__ WaT, __bf16* __restrict__ hb,
    float* __restrict__ a_s, float* __restrict__ a_d, int M)
{
    __shared__ __align__(16) __bf16 As[2][64 * 32];    // 2 x 4KB
    __shared__ __align__(16) __bf16 Bs[2][256 * 32];   // 2 x 16KB

    const int tid  = threadIdx.x;
    const int w    = tid >> 6, lane = tid & 63;
    const int wm   = w >> 2,   wn   = w & 3;           // 2x4 waves, 32x64 each
    const int quad = lane >> 4, l16 = lane & 15;
    const int bm   = blockIdx.x * 64;

    const bool astage = (tid < 256);
    const int r0   = tid >> 2;
    const int cpos = tid & 3;
    const int cxor = (cpos ^ (r0 & 3)) << 3;
    int grow = bm + r0; if (grow > M - 1) grow = M - 1;
    const float* xrow = x + (size_t)grow * D_IN;

    const int brsub = lane >> 2;
    const int bc    = lane & 3;

    f32x4 acc[2][4];
    #pragma unroll
    for (int i = 0; i < 2; i++)
        #pragma unroll
        for (int j = 0; j < 4; j++)
            acc[i][j] = (f32x4){0.f, 0.f, 0.f, 0.f};
    f32x4 accA[2];
    #pragma unroll
    for (int i = 0; i < 2; i++) accA[i] = (f32x4){0.f, 0.f, 0.f, 0.f};

    const bool att = (wn == 0);
    const __bf16* warow = WaT + (size_t)l16 * KPAD + quad * 8;

    auto stageB = [&](int buf, int k0) {
        #pragma unroll
        for (int off = 0; off < 16384; off += 8192) {
            int o2 = off + w * 1024;
            int r = (o2 >> 6) + brsub;
            int chunk = bc ^ (r & 3);
            const __bf16* gp = WbT + (size_t)r * KPAD + k0 + chunk * 8;
            __builtin_amdgcn_global_load_lds(
                (const __attribute__((address_space(1))) void*)gp,
                (__attribute__((address_space(3))) void*)((char*)&Bs[buf][0] + o2),
                16, 0, 0);
        }
    };

    auto compute = [&](int buf, const bf16x8& attfrag) {
        bf16x8 af[2], bfr[4];
        #pragma unroll
        for (int mt = 0; mt < 2; mt++) {
            int r = wm * 32 + mt * 16 + l16;
            af[mt] = *(const bf16x8*)&As[buf][r * 32 + (quad ^ (r & 3)) * 8];
        }
        #pragma unroll
        for (int nt = 0; nt < 4; nt++) {
            int r = wn * 64 + nt * 16 + l16;
            bfr[nt] = *(const bf16x8*)&Bs[buf][r * 32 + (quad ^ (r & 3)) * 8];
        }
        #pragma unroll
        for (int mt = 0; mt < 2; mt++)
            #pragma unroll
            for (int nt = 0; nt < 4; nt++)
                acc[mt][nt] = __builtin_amdgcn_mfma_f32_16x16x32_bf16(
                    af[mt], bfr[nt], acc[mt][nt], 0, 0, 0);
        if (att) {
            #pragma unroll
            for (int mt = 0; mt < 2; mt++)
                accA[mt] = __builtin_amdgcn_mfma_f32_16x16x32_bf16(
                    af[mt], attfrag, accA[mt], 0, 0, 0);
        }
    };

    // prologue: prep buf0 for k=0
    f32x4 x0, x1;
    if (astage) xload8(xrow, 0 + cxor, x0, x1);
    bf16x8 attc = {};
    if (att) attc = *(const bf16x8*)(warow + 0);
    stageB(0, 0);
    if (astage) *(bf16x8*)&As[0][r0 * 32 + cpos * 8] = cvt8(x0, x1);
    __syncthreads();

    #pragma unroll 2
    for (int p = 0; p < 32; ++p) {
        const int buf = p & 1;
        const int kn  = (p + 1) * 32;
        bf16x8 attn = {};
        if (p < 31) {
            if (astage) xload8(xrow, kn + cxor, x0, x1);
            if (att) attn = *(const bf16x8*)(warow + kn);
            stageB(buf ^ 1, kn);
        }
        compute(buf, attc);
        __builtin_amdgcn_sched_barrier(0);     // pin cvt/ds_write BELOW MFMAs
        if (p < 31) {
            if (astage) *(bf16x8*)&As[buf ^ 1][r0 * 32 + cpos * 8] = cvt8(x0, x1);
        }
        attc = attn;
        __syncthreads();
    }

    // epilogue: hb bf16
    #pragma unroll
    for (int nt = 0; nt < 4; nt++) {
        int col = wn * 64 + nt * 16 + l16;
        #pragma unroll
        for (int mt = 0; mt < 2; mt++) {
            int row0 = bm + wm * 32 + mt * 16 + quad * 4;
            #pragma unroll
            for (int rr = 0; rr < 4; rr++) {
                int row = row0 + rr;
                if (row < M)
                    hb[(size_t)row * 256 + col] = (__bf16)acc[mt][nt][rr];
            }
        }
    }
    if (att) {
        #pragma unroll
        for (int mt = 0; mt < 2; mt++) {
            int row0 = bm + wm * 32 + mt * 16 + quad * 4;
            #pragma unroll
            for (int rr = 0; rr < 4; rr++) {
                int row = row0 + rr;
                if (row < M) {
                    float v = accA[mt][rr];
                    if (l16 < 8) a_s[row * NHEAD + l16] = v;
                    else         a_d[row * NHEAD + (l16 - 8)] = v;
                }
            }
        }
    }
}

// ---------------------------------------------------------------------------
// FUSED gat_aggregate + gemm_zdr. Block = 64 nodes, 512 threads (8 waves).
// De-barriered phase 1 kept (embT direct from L2-hot global; 16 barrier
// drains deleted; Bs buffer removed -> 49KB LDS). launch_bounds back to
// (512,4) — the (512,6) VGPR squeeze regressed gemm1 badly in r12.
// ---------------------------------------------------------------------------
#define HROW 264

__device__ __forceinline__ float leaky(float x) {
    return x > 0.f ? x : NEG_SLOPE * x;
}

__global__ __launch_bounds__(512, 4) void gat_zdr(
    const __bf16* __restrict__ hb, const float* __restrict__ a_s,
    const float* __restrict__ a_d, const int* __restrict__ cnt,
    const int* __restrict__ slots, const float* __restrict__ bias,
    const __bf16* __restrict__ embT, const __bf16* __restrict__ d1T,
    const __bf16* __restrict__ d2T, const float* __restrict__ emb_b,
    const float* __restrict__ dec_b1, const float* __restrict__ dec_b2,
    float* __restrict__ z, float* __restrict__ recon, int M)
{
    __shared__ __align__(16) __bf16 hgatS[64 * HROW];   // 33 KB
    __shared__ __align__(16) __bf16 zS[64 * 64];        // 8 KB
    __shared__ __align__(16) __bf16 Bs2[2 * 32 * 32];   // 4 KB (d1T)
    __shared__ __align__(16) __bf16 dS[64 * 32];        // 4 KB

    const int tid  = threadIdx.x;
    const int wv   = tid >> 6, lane = tid & 63;
    const int quad = lane >> 4, l16 = lane & 15;
    const int bm   = blockIdx.x * 64;

    // stage d1T once (waves 0,1 active inside stage_tile's loop)
    stage_tile(Bs2,        d1T, 0, 31, 64, 0,  32, wv, lane, 4096);
    stage_tile(Bs2 + 1024, d1T, 0, 31, 64, 32, 32, wv, lane, 4096);

    // ---- phase 0: GAT aggregation, dual-node interleaved chains ----
    {
        const int hh = lane >> 3;
        const int fo = (lane & 7) * 4;
        const f32x4 bv = *(const f32x4*)(bias + lane * 4);

        auto gather4 = [&](int base, int e, float adn, f32x4& acc, float& denom) {
            const int4 ss = *(const int4*)(slots + base + e);
            float l0 = a_s[ss.x * NHEAD + hh], l1 = a_s[ss.y * NHEAD + hh];
            float l2 = a_s[ss.z * NHEAD + hh], l3 = a_s[ss.w * NHEAD + hh];
            bf16x4 h0 = *(const bf16x4*)(hb + (size_t)ss.x * 256 + hh * F_HID + fo);
            bf16x4 h1 = *(const bf16x4*)(hb + (size_t)ss.y * 256 + hh * F_HID + fo);
            bf16x4 h2 = *(const bf16x4*)(hb + (size_t)ss.z * 256 + hh * F_HID + fo);
            bf16x4 h3 = *(const bf16x4*)(hb + (size_t)ss.w * 256 + hh * F_HID + fo);
            float p0 = __expf(leaky(l0 + adn)), p1 = __expf(leaky(l1 + adn));
            float p2 = __expf(leaky(l2 + adn)), p3 = __expf(leaky(l3 + adn));
            denom += (p0 + p1) + (p2 + p3);
            acc.x += p0*(float)h0[0] + p1*(float)h1[0] + p2*(float)h2[0] + p3*(float)h3[0];
            acc.y += p0*(float)h0[1] + p1*(float)h1[1] + p2*(float)h2[1] + p3*(float)h3[1];
            acc.z += p0*(float)h0[2] + p1*(float)h1[2] + p2*(float)h2[2] + p3*(float)h3[2];
            acc.w += p0*(float)h0[3] + p1*(float)h1[3] + p2*(float)h2[3] + p3*(float)h3[3];
        };
        auto gather1 = [&](int base, int e, float adn, f32x4& acc, float& denom) {
            int s = slots[base + e];
            float pe = __expf(leaky(a_s[s * NHEAD + hh] + adn));
            denom += pe;
            bf16x4 hv = *(const bf16x4*)(hb + (size_t)s * 256 + hh * F_HID + fo);
            acc.x += pe * (float)hv[0]; acc.y += pe * (float)hv[1];
            acc.z += pe * (float)hv[2]; acc.w += pe * (float)hv[3];
        };

        #pragma unroll
        for (int i = 0; i < 4; i++) {
            const int nA = bm + wv * 8 + i * 2;
            const int nB = nA + 1;
            const bool vA = nA < M, vB = nB < M;
            const int iA = vA ? nA : M - 1;
            const int iB = vB ? nB : M - 1;
            const int baseA = iA * MAXDEG, baseB = iB * MAXDEG;
            const int cA = vA ? cnt[iA] : 0;
            const int cB = vB ? cnt[iB] : 0;
            const float adnA = a_d[iA * NHEAD + hh];
            const float adnB = a_d[iB * NHEAD + hh];

            // self loops
            float pA = __expf(leaky(a_s[iA * NHEAD + hh] + adnA));
            float pB = __expf(leaky(a_s[iB * NHEAD + hh] + adnB));
            float denA = pA, denB = pB;
            f32x4 accA, accB;
            {
                bf16x4 hvA = *(const bf16x4*)(hb + (size_t)iA * 256 + hh * F_HID + fo);
                bf16x4 hvB = *(const bf16x4*)(hb + (size_t)iB * 256 + hh * F_HID + fo);
                accA.x = pA*(float)hvA[0]; accA.y = pA*(float)hvA[1];
                accA.z = pA*(float)hvA[2]; accA.w = pA*(float)hvA[3];
                accB.x = pB*(float)hvB[0]; accB.y = pB*(float)hvB[1];
                accB.z = pB*(float)hvB[2]; accB.w = pB*(float)hvB[3];
            }
            int eA = 0, eB = 0;
            while (eA + 8 <= cA && eB + 8 <= cB) {
                gather4(baseA, eA,     adnA, accA, denA);
                gather4(baseB, eB,     adnB, accB, denB);
                gather4(baseA, eA + 4, adnA, accA, denA);
                gather4(baseB, eB + 4, adnB, accB, denB);
                eA += 8; eB += 8;
            }
            while (eA + 8 <= cA) {
                gather4(baseA, eA, adnA, accA, denA);
                gather4(baseA, eA + 4, adnA, accA, denA);
                eA += 8;
            }
            while (eB + 8 <= cB) {
                gather4(baseB, eB, adnB, accB, denB);
                gather4(baseB, eB + 4, adnB, accB, denB);
                eB += 8;
            }
            if (eA + 4 <= cA) { gather4(baseA, eA, adnA, accA, denA); eA += 4; }
            if (eB + 4 <= cB) { gather4(baseB, eB, adnB, accB, denB); eB += 4; }
            for (; eA < cA; eA++) gather1(baseA, eA, adnA, accA, denA);
            for (; eB < cB; eB++) gather1(baseB, eB, adnB, accB, denB);

            if (vA) {
                float inv = 1.0f / denA;
                float o0 = accA.x * inv + bv.x, o1 = accA.y * inv + bv.y;
                float o2 = accA.z * inv + bv.z, o3 = accA.w * inv + bv.w;
                o0 = o0 > 0.f ? o0 : 0.f; o1 = o1 > 0.f ? o1 : 0.f;
                o2 = o2 > 0.f ? o2 : 0.f; o3 = o3 > 0.f ? o3 : 0.f;
                bf16x4 ob;
                ob[0] = (__bf16)o0; ob[1] = (__bf16)o1;
                ob[2] = (__bf16)o2; ob[3] = (__bf16)o3;
                *(bf16x4*)&hgatS[(wv * 8 + i * 2) * HROW + lane * 4] = ob;
            }
            if (vB) {
                float inv = 1.0f / denB;
                float o0 = accB.x * inv + bv.x, o1 = accB.y * inv + bv.y;
                float o2 = accB.z * inv + bv.z, o3 = accB.w * inv + bv.w;
                o0 = o0 > 0.f ? o0 : 0.f; o1 = o1 > 0.f ? o1 : 0.f;
                o2 = o2 > 0.f ? o2 : 0.f; o3 = o3 > 0.f ? o3 : 0.f;
                bf16x4 ob;
                ob[0] = (__bf16)o0; ob[1] = (__bf16)o1;
                ob[2] = (__bf16)o2; ob[3] = (__bf16)o3;
                *(bf16x4*)&hgatS[(wv * 8 + i * 2 + 1) * HROW + lane * 4] = ob;
            }
        }
    }
    __syncthreads();   // hgatS complete; also drains Bs2 gload_lds

    // ---- phase 1: z = hgatS @ embT, DE-BARRIERED ----
    // embT fragments read directly from global (32KB, L2-broadcast-hot):
    // 8 fragments/wave total. Zero barriers in the K-loop.
    const int wm  = wv >> 2;
    const int wn4 = wv & 3;
    f32x4 acc[2];
    acc[0] = (f32x4){0,0,0,0}; acc[1] = (f32x4){0,0,0,0};

    const __bf16* embrow = embT + (size_t)(wn4 * 16 + l16) * 256 + quad * 8;
    #pragma unroll
    for (int k0 = 0; k0 < 256; k0 += 32) {
        bf16x8 af[2];
        #pragma unroll
        for (int mt = 0; mt < 2; mt++) {
            int r = wm * 32 + mt * 16 + l16;
            af[mt] = *(const bf16x8*)&hgatS[r * HROW + k0 + quad * 8];
        }
        bf16x8 bfr = *(const bf16x8*)(embrow + k0);
        #pragma unroll
        for (int mt = 0; mt < 2; mt++)
            acc[mt] = __builtin_amdgcn_mfma_f32_16x16x32_bf16(af[mt], bfr, acc[mt], 0, 0, 0);
    }

    // epilogue 1: z fp32 -> global; z bf16 -> zS (stage_tile XOR layout)
    {
        int col = wn4 * 16 + l16;
        float bv = emb_b[col];
        int t = col >> 5, cch = (col >> 3) & 3, j = col & 7;
        #pragma unroll
        for (int mt = 0; mt < 2; mt++) {
            int rl0 = wm * 32 + mt * 16 + quad * 4;
            #pragma unroll
            for (int rr = 0; rr < 4; rr++) {
                int rl = rl0 + rr;
                int row = bm + rl;
                float v = acc[mt][rr] + bv;
                if (row < M) z[(size_t)row * D_EMB + col] = v;
                zS[t * 2048 + rl * 32 + (cch ^ (rl & 3)) * 8 + j] = (__bf16)v;
            }
        }
    }
    __syncthreads();

    // ---- phase 2: d = relu(zS @ d1T + b1), waves with wn4<2 ----
    if (wn4 < 2) {
        f32x4 accd[2];
        accd[0] = (f32x4){0,0,0,0}; accd[1] = (f32x4){0,0,0,0};
        #pragma unroll
        for (int t = 0; t < 2; t++) {
            bf16x8 af[2], bfr;
            #pragma unroll
            for (int mt = 0; mt < 2; mt++) {
                int r = wm * 32 + mt * 16 + l16;
                af[mt] = *(const bf16x8*)&zS[t * 2048 + r * 32 + (quad ^ (r & 3)) * 8];
            }
            {
                int r = wn4 * 16 + l16;
                bfr = *(const bf16x8*)&Bs2[t * 1024 + r * 32 + (quad ^ (r & 3)) * 8];
            }
            #pragma unroll
            for (int mt = 0; mt < 2; mt++)
                accd[mt] = __builtin_amdgcn_mfma_f32_16x16x32_bf16(af[mt], bfr, accd[mt], 0, 0, 0);
        }
        int col = wn4 * 16 + l16;
        float bv = dec_b1[col];
        int cc = col >> 3, j = col & 7;
        #pragma unroll
        for (int mt = 0; mt < 2; mt++) {
            int rl0 = wm * 32 + mt * 16 + quad * 4;
            #pragma unroll
            for (int rr = 0; rr < 4; rr++) {
                int rl = rl0 + rr;
                float v = accd[mt][rr] + bv;
                v = v > 0.f ? v : 0.f;
                dS[rl * 32 + (cc ^ (rl & 3)) * 8 + j] = (__bf16)v;
            }
        }
    }
    __syncthreads();

    // ---- phase 3: recon = d @ d2T + b2 (operand-swapped, f32x4 stores) ----
    {
        const int wtt = wv & 3;
        bf16x8 daf[2];
        #pragma unroll
        for (int mt = 0; mt < 2; mt++) {
            int r = wm * 32 + mt * 16 + l16;
            daf[mt] = *(const bf16x8*)&dS[r * 32 + (quad ^ (r & 3)) * 8];
        }
        for (int tt = wtt; tt < 63; tt += 4) {
            int crow = tt * 16 + l16;
            if (crow > D_IN - 1) crow = D_IN - 1;
            bf16x8 bfr = *(const bf16x8*)&d2T[(size_t)crow * 32 + quad * 8];
            f32x4 a[2];
            #pragma unroll
            for (int mt = 0; mt < 2; mt++) {
                a[mt] = (f32x4){0.f, 0.f, 0.f, 0.f};
                a[mt] = __builtin_amdgcn_mfma_f32_16x16x32_bf16(bfr, daf[mt], a[mt], 0, 0, 0);
            }
            int col0 = tt * 16 + quad * 4;
            if (col0 + 3 < D_IN) {
                f32x4 bv = *(const f32x4*)&dec_b2[col0];
                #pragma unroll
                for (int mt = 0; mt < 2; mt++) {
                    int row = bm + wm * 32 + mt * 16 + l16;
                    if (row < M) {
                        f32x4 o;
                        o.x = a[mt].x + bv.x; o.y = a[mt].y + bv.y;
                        o.z = a[mt].z + bv.z; o.w = a[mt].w + bv.w;
                        *(f32x4*)&recon[(size_t)row * D_IN + col0] = o;
                    }
                }
            }
        }
    }
}

// ---------------------------------------------------------------------------
extern "C" void kernel_launch(void* const* d_in, const int* in_sizes, int n_in,
                              void* d_out, int out_size, void* d_ws, size_t ws_size,
                              hipStream_t stream)
{
    const float* x        = (const float*)d_in[0];
    const int*   eidx     = (const int*)  d_in[1];
    const float* W        = (const float*)d_in[3];
    const float* att_src  = (const float*)d_in[4];
    const float* att_dst  = (const float*)d_in[5];
    const float* bias_gat = (const float*)d_in[6];
    const float* emb_W    = (const float*)d_in[7];
    const float* emb_b    = (const float*)d_in[8];
    const float* dec_W1   = (const float*)d_in[9];
    const float* dec_b1   = (const float*)d_in[10];
    const float* dec_W2   = (const float*)d_in[11];
    const float* dec_b2   = (const float*)d_in[12];

    float* out   = (float*)d_out;
    float* recon = out;                             // [30000,1000] fp32
    float* z     = out + (size_t)N_NODES * D_IN;    // [30000,64]   fp32

    char* ws = (char*)d_ws;
    size_t o = 0;
    auto alloc = [&](size_t bytes) { char* p = ws + o; o = (o + bytes + 255) & ~(size_t)255; return p; };
    __bf16* hb      = (__bf16*)alloc((size_t)N_NODES * 256 * 2);
    __bf16* WbT     = (__bf16*)alloc((size_t)256 * KPAD * 2);
    __bf16* embT    = (__bf16*)alloc((size_t)D_EMB * 256 * 2);
    __bf16* d1T     = (__bf16*)alloc((size_t)F_HID * D_EMB * 2);
    __bf16* d2T     = (__bf16*)alloc((size_t)D_IN * F_HID * 2);
    __bf16* WaT     = (__bf16*)alloc((size_t)16 * KPAD * 2);
    float*  a_s     = (float*) alloc((size_t)N_NODES * NHEAD * 4);
    float*  a_d     = (float*) alloc((size_t)N_NODES * NHEAD * 4);
    int*    slots   = (int*)   alloc((size_t)N_NODES * MAXDEG * 4);
    int*    cnt     = (int*)   alloc((size_t)N_NODES * 4);

    // 0. zero cnt (graph-capturable async memset)
    hipMemsetAsync(cnt, 0, (size_t)N_NODES * 4, stream);

    // 1. tiled weight transposes + WaT fold + XCD-sharded edge scatter
    cvt_w<<<WBT_TILES + REST_BLOCKS + WA_BLOCKS + SC_BLOCKS, 256, 0, stream>>>(
        W, emb_W, dec_W1, dec_W2, att_src, att_dst,
        WbT, embT, d1T, d2T, WaT, eidx, cnt, slots);

    // 2. h = x @ W -> hb bf16; a_s/a_d folded
    gemm1_fused<<<GEMM1_BLOCKS, 512, 0, stream>>>(
        x, WbT, WaT, hb, a_s, a_d, N_NODES);

    // 3. fused GAT aggregation + z + d + recon (de-barriered phase 1)
    gat_zdr<<<GEMM1_BLOCKS, 512, 0, stream>>>(
        hb, a_s, a_d, cnt, slots, bias_gat,
        embT, d1T, d2T, emb_b, dec_b1, dec_b2, z, recon, N_NODES);
}